// Round 10
// baseline (277.805 us; speedup 1.0000x reference)
//
#include <hip/hip_runtime.h>
#include <hip/hip_bf16.h>
#include <cstdint>
#include <math.h>

constexpr int PB = 8;
constexpr int NS = 1024;
constexpr int DM = 768;
constexpr int NH = 12;
constexpr int HSZ = 64;
// reference MULTIPLIES scores by sqrt(head_size)=8; folded into q at qkv epilogue.
constexpr float EOFF = 88.0f;   // fixed softmax offset: p = exp(s-EOFF)/sum

typedef short bf16x8 __attribute__((ext_vector_type(8)));
typedef float floatx4 __attribute__((ext_vector_type(4)));

__device__ __forceinline__ ushort f2bf(float x) {
    __hip_bfloat16 b = __float2bfloat16(x);
    return *reinterpret_cast<ushort*>(&b);
}
__device__ __forceinline__ float bf2f(ushort u) {
    __hip_bfloat16 b = *reinterpret_cast<__hip_bfloat16*>(&u);
    return __bfloat162float(b);
}

#define GLDS(g, l)                                                             \
    __builtin_amdgcn_global_load_lds(                                          \
        (const __attribute__((address_space(1))) void*)(g),                    \
        (__attribute__((address_space(3))) void*)(l), 16, 0, 0)

// ---------------- split fp32 -> (hi, lo) bf16, elementwise ----------------
__global__ void split_kernel(const float* __restrict__ x, ushort* __restrict__ hi,
                             ushort* __restrict__ lo, int n4)
{
    int i = blockIdx.x * blockDim.x + threadIdx.x;
    const int stride = gridDim.x * blockDim.x;
    for (; i < n4; i += stride) {
        const float4 v = ((const float4*)x)[i];
        ushort4 h, l;
        h.x = f2bf(v.x); l.x = f2bf(v.x - bf2f(h.x));
        h.y = f2bf(v.y); l.y = f2bf(v.y - bf2f(h.y));
        h.z = f2bf(v.z); l.z = f2bf(v.z - bf2f(h.z));
        h.w = f2bf(v.w); l.w = f2bf(v.w - bf2f(h.w));
        ((ushort4*)hi)[i] = h;
        ((ushort4*)lo)[i] = l;
    }
}

// ------------- split + transpose: w (K x N) -> wT hi/lo (N x K) -------------
__global__ void splitT_kernel(const float* __restrict__ w, ushort* __restrict__ hiT,
                              ushort* __restrict__ loT, int K, int N)
{
    __shared__ float tile[32][33];
    const int tx = threadIdx.x, ty = threadIdx.y;   // (32, 8)
    const int bx = blockIdx.x, by = blockIdx.y;     // N/32, K/32
    #pragma unroll
    for (int r = 0; r < 4; ++r)
        tile[ty + r*8][tx] = w[(size_t)(by*32 + ty + r*8) * N + bx*32 + tx];
    __syncthreads();
    #pragma unroll
    for (int r = 0; r < 4; ++r) {
        const int n = bx*32 + ty + r*8;
        const int k = by*32 + tx;
        const float v = tile[tx][ty + r*8];
        const ushort h = f2bf(v);
        hiT[(size_t)n * K + k] = h;
        loT[(size_t)n * K + k] = f2bf(v - bf2f(h));
    }
}

// ---------------- 3-pass split-bf16 MFMA GEMM, q/k columns only ----------------
// C = A(MxK) @ B(KxN), N = 1536 (q then k heads). 128x128 tile, BK=32.
// GRID: x = m-block (64), y = n-block (12). flat id = x + 64y -> id%8 = x%8:
// the 12 n-blocks sharing one A-tile co-locate on one XCD (L2 reuse).
// Epilogue: scatter q (scaled by 8) / k as split hi/lo bf16 (P,H,N,64).
__global__ __launch_bounds__(256, 2)
void gemm_qk(const ushort* __restrict__ Ah, const ushort* __restrict__ Al,
             const ushort* __restrict__ Bh, const ushort* __restrict__ Bl,
             const float* __restrict__ bias,
             ushort* __restrict__ qh, ushort* __restrict__ ql,
             ushort* __restrict__ kh, ushort* __restrict__ kl, int K)
{
    __shared__ __align__(16) ushort Ah_s[128*32];
    __shared__ __align__(16) ushort Al_s[128*32];
    __shared__ __align__(16) ushort Bh_s[128*32];
    __shared__ __align__(16) ushort Bl_s[128*32];

    const int t    = threadIdx.x;
    const int w    = t >> 6;
    const int lane = t & 63;
    const int l15  = lane & 15;
    const int quad = lane >> 4;
    const int wm = w >> 1, wn = w & 1;
    const int m0 = blockIdx.x * 128, n0 = blockIdx.y * 128;   // XCD swizzle

    floatx4 acc[4][4];
    #pragma unroll
    for (int i = 0; i < 4; ++i)
        #pragma unroll
        for (int j = 0; j < 4; ++j) acc[i][j] = floatx4{0.f, 0.f, 0.f, 0.f};

    const int srow = lane >> 2;
    const int sseg = (lane & 3) ^ (srow & 3);
    const int r0   = w * 32;
    const size_t aBase = (size_t)(m0 + r0 + srow) * K + sseg * 8;
    const size_t bBase = (size_t)(n0 + r0 + srow) * K + sseg * 8;
    const int ldsBase = r0 * 32;
    const int fsl = (quad ^ (l15 & 3)) * 8;

    for (int k0 = 0; k0 < K; k0 += 32) {
        #pragma unroll
        for (int j = 0; j < 2; ++j) {
            const size_t ga = aBase + (size_t)j * 16 * K + k0;
            const size_t gb = bBase + (size_t)j * 16 * K + k0;
            const int lb = ldsBase + j * 512;
            GLDS(Ah + ga, Ah_s + lb);
            GLDS(Al + ga, Al_s + lb);
            GLDS(Bh + gb, Bh_s + lb);
            GLDS(Bl + gb, Bl_s + lb);
        }
        __syncthreads();

        bf16x8 fah[4], fal[4], fbh[4], fbl[4];
        #pragma unroll
        for (int i = 0; i < 4; ++i) {
            const int ra = (wm*64 + i*16 + l15) * 32 + fsl;
            fah[i] = *(const bf16x8*)(Ah_s + ra);
            fal[i] = *(const bf16x8*)(Al_s + ra);
            const int rb = (wn*64 + i*16 + l15) * 32 + fsl;
            fbh[i] = *(const bf16x8*)(Bh_s + rb);
            fbl[i] = *(const bf16x8*)(Bl_s + rb);
        }
        #pragma unroll
        for (int mt = 0; mt < 4; ++mt)
            #pragma unroll
            for (int nt = 0; nt < 4; ++nt) {
                acc[mt][nt] = __builtin_amdgcn_mfma_f32_16x16x32_bf16(fah[mt], fbh[nt], acc[mt][nt], 0, 0, 0);
                acc[mt][nt] = __builtin_amdgcn_mfma_f32_16x16x32_bf16(fah[mt], fbl[nt], acc[mt][nt], 0, 0, 0);
                acc[mt][nt] = __builtin_amdgcn_mfma_f32_16x16x32_bf16(fal[mt], fbh[nt], acc[mt][nt], 0, 0, 0);
            }
        __syncthreads();
    }

    const int jbase = n0 + wn*64;
    const int c  = jbase / DM;
    const int hh = (jbase % DM) >> 6;
    const int pp = (m0 + wm*64) >> 10;
    const size_t head = (size_t)pp * NH + hh;
    ushort* dh = (c == 0 ? qh : kh);
    ushort* dl = (c == 0 ? ql : kl);
    const float qscale = (c == 0) ? 8.0f : 1.0f;   // fold score scale into q (exact)
    #pragma unroll
    for (int nt = 0; nt < 4; ++nt) {
        const int s = nt*16 + l15;
        const float bval = bias[jbase + s];
        #pragma unroll
        for (int mt = 0; mt < 4; ++mt) {
            const int tok0 = m0 + wm*64 + mt*16 + quad*4;
            const int nn0  = tok0 & 1023;
            #pragma unroll
            for (int r = 0; r < 4; ++r) {
                const float v = (acc[mt][nt][r] + bval) * qscale;
                const ushort hi = f2bf(v);
                dh[(head*NS + nn0 + r) * HSZ + s] = hi;
                dl[(head*NS + nn0 + r) * HSZ + s] = f2bf(v - bf2f(hi));
            }
        }
    }
}

// ---------------- single-pass bf16 MFMA GEMM, BK=64 ----------------
// GRID: x = m-block (64), y = n-block -> same-A blocks share an XCD.
template <int MODE>
__global__ __launch_bounds__(256, 3)
void gemm_1p(const ushort* __restrict__ Ah, const ushort* __restrict__ Bh,
             const float* __restrict__ bias, float* __restrict__ outf,
             ushort* __restrict__ vt, int K)
{
    __shared__ __align__(16) ushort As[128*64];
    __shared__ __align__(16) ushort Bs[128*64];

    const int t    = threadIdx.x;
    const int w    = t >> 6;
    const int lane = t & 63;
    const int l15  = lane & 15;
    const int quad = lane >> 4;
    const int wm = w >> 1, wn = w & 1;
    const int m0 = blockIdx.x * 128, n0 = blockIdx.y * 128;   // XCD swizzle

    floatx4 acc[4][4];
    #pragma unroll
    for (int i = 0; i < 4; ++i)
        #pragma unroll
        for (int j = 0; j < 4; ++j) acc[i][j] = floatx4{0.f, 0.f, 0.f, 0.f};

    const int srow8 = lane >> 3;
    const int sslot = lane & 7;

    for (int k0 = 0; k0 < K; k0 += 64) {
        #pragma unroll
        for (int j = 0; j < 4; ++j) {
            const int row = w*32 + j*8 + srow8;
            const int seg = sslot ^ (row & 7);
            const int ldst = (w*32 + j*8) * 64;
            GLDS(Ah + (size_t)(m0 + row) * K + k0 + seg*8, As + ldst);
            GLDS(Bh + (size_t)(n0 + row) * K + k0 + seg*8, Bs + ldst);
        }
        __syncthreads();

        #pragma unroll
        for (int h2 = 0; h2 < 2; ++h2) {
            bf16x8 fa[4], fb[4];
            #pragma unroll
            for (int i = 0; i < 4; ++i) {
                const int sl = ((h2*4 + quad) ^ (l15 & 7)) * 8;
                fa[i] = *(const bf16x8*)(As + (wm*64 + i*16 + l15) * 64 + sl);
                fb[i] = *(const bf16x8*)(Bs + (wn*64 + i*16 + l15) * 64 + sl);
            }
            #pragma unroll
            for (int mt = 0; mt < 4; ++mt)
                #pragma unroll
                for (int nt = 0; nt < 4; ++nt)
                    acc[mt][nt] = __builtin_amdgcn_mfma_f32_16x16x32_bf16(fa[mt], fb[nt], acc[mt][nt], 0, 0, 0);
        }
        __syncthreads();
    }

    if (MODE == 0) {
        #pragma unroll
        for (int nt = 0; nt < 4; ++nt) {
            const int col = n0 + wn*64 + nt*16 + l15;
            const float bval = bias[col];
            #pragma unroll
            for (int mt = 0; mt < 4; ++mt) {
                const int row0 = m0 + wm*64 + mt*16 + quad*4;
                #pragma unroll
                for (int r = 0; r < 4; ++r)
                    outf[(size_t)(row0 + r) * DM + col] = acc[mt][nt][r] + bval;
            }
        }
    } else {
        const int jbase = n0 + wn*64;
        const int hh = jbase >> 6;
        const int pp = (m0 + wm*64) >> 10;
        const size_t head = (size_t)pp * NH + hh;
        #pragma unroll
        for (int nt = 0; nt < 4; ++nt) {
            const int s = nt*16 + l15;
            const float bval = bias[jbase + s];
            #pragma unroll
            for (int mt = 0; mt < 4; ++mt) {
                const int tok0 = m0 + wm*64 + mt*16 + quad*4;
                const int nn0  = tok0 & 1023;
                ushort4 pk;
                pk.x = f2bf(acc[mt][nt][0] + bval);
                pk.y = f2bf(acc[mt][nt][1] + bval);
                pk.z = f2bf(acc[mt][nt][2] + bval);
                pk.w = f2bf(acc[mt][nt][3] + bval);
                *(ushort4*)(vt + (head*HSZ + s) * NS + nn0) = pk;
            }
        }
    }
}

// ---------------- mask @ V per (p,h): mv[p][h][c] ----------------
__global__ void mv_kernel(const float* __restrict__ mask, const ushort* __restrict__ vt,
                          float* __restrict__ mv)
{
    __shared__ float red[4][64];
    const int ph = blockIdx.x;
    const int t  = threadIdx.x;
    const int c  = t & 63, part = t >> 6;
    const ushort* vrow = vt + ((size_t)ph * HSZ + c) * NS + part * 256;
    const float*  mrow = mask + (size_t)(ph / NH) * NS + part * 256;
    float acc = 0.f;
    for (int k = 0; k < 256; k += 4) {
        const ushort4 v4 = *(const ushort4*)(vrow + k);
        const float4  m4 = *(const float4*)(mrow + k);
        acc += m4.x * bf2f(v4.x) + m4.y * bf2f(v4.y)
             + m4.z * bf2f(v4.z) + m4.w * bf2f(v4.w);
    }
    red[part][c] = acc;
    __syncthreads();
    if (t < 64)
        mv[(size_t)ph * HSZ + t] = red[0][t] + red[1][t] + red[2][t] + red[3][t];
}

// ---------------- MFMA flash attention, double-buffered staging ----------------
// GRID: x = ph (96 = p*12+h), y = qt (8); id%8 = ph%8 pins all q-tiles of one
// (p,h) to one XCD (r9: FETCH 197->46 MB). r9 showed MFMA=VALU=Occ=27% -- the
// single-buffered K-loop's vmcnt(0) drain at each barrier serialized ~500-900
// cyc of L2/HBM latency per tile at only 3 blocks/CU. Fix: 2x LDS buffers;
// stage(kt+1) issues right after the barrier and drains at the NEXT barrier,
// overlapping the whole compute phase. LDS 48KB -> still 3 blocks/CU.
// VGPR: keep min-waves 4 (128 cap); forcing 6 spilled (r8: 745 MB scratch).
// S^T = K.Q^T permuted-key (register P, no LDS round-trip); fixed-offset
// softmax exp(s-88), l reduced in epilogue; ctx = O/l + mv, bf16.
__global__ __launch_bounds__(256, 4)
void attn_mfma_kernel(const ushort* __restrict__ qh, const ushort* __restrict__ ql,
                      const ushort* __restrict__ kh, const ushort* __restrict__ kl,
                      const ushort* __restrict__ vt, const float* __restrict__ mv,
                      ushort* __restrict__ ctx)
{
    __shared__ __align__(16) ushort khs[2][64*64];
    __shared__ __align__(16) ushort kls[2][64*64];
    __shared__ __align__(16) ushort vs [2][64*64];

    const int t    = threadIdx.x;
    const int w    = t >> 6;
    const int lane = t & 63;
    const int l15  = lane & 15;
    const int quad = lane >> 4;
    const int ph = blockIdx.x, qt = blockIdx.y;    // XCD swizzle
    const int h  = ph % NH,    p  = ph / NH;
    const size_t headoff = ((size_t)p * NH + h) * (size_t)(NS * HSZ);

    // persistent Q frags (B-operand): row = qt*128 + w*32 + rt*16 + l15
    bf16x8 qfh[2][2], qfl[2][2];
    #pragma unroll
    for (int rt = 0; rt < 2; ++rt) {
        const size_t r = (size_t)(qt*128 + w*32 + rt*16 + l15);
        const ushort* bh = qh + headoff + r * HSZ + quad*8;
        const ushort* bl = ql + headoff + r * HSZ + quad*8;
        qfh[rt][0] = *(const bf16x8*)(bh);
        qfh[rt][1] = *(const bf16x8*)(bh + 32);
        qfl[rt][0] = *(const bf16x8*)(bl);
        qfl[rt][1] = *(const bf16x8*)(bl + 32);
    }

    floatx4 o[2][4];
    float lsum[2] = {0.f, 0.f};
    #pragma unroll
    for (int rt = 0; rt < 2; ++rt)
        #pragma unroll
        for (int tc = 0; tc < 4; ++tc) o[rt][tc] = floatx4{0.f, 0.f, 0.f, 0.f};

    const int srow8 = lane >> 3;
    const int sslot = lane & 7;
    const int xs = l15 & 7;         // read-side unswizzle key

    auto stage = [&](int kt, int buf) {
        #pragma unroll
        for (int j = 0; j < 2; ++j) {
            const int row  = w*16 + j*8 + srow8;                       // 0..63
            const int segK = sslot ^ ((row & 3) | (((row >> 3) & 1) << 2));
            const int segV = sslot ^ (row & 7);
            const size_t gk = headoff + (size_t)(kt*64 + row) * HSZ + segK*8;
            const size_t gv = headoff + (size_t)row * NS + kt*64 + segV*8;
            const int ldst = (w*16 + j*8) * 64;
            GLDS(kh + gk, khs[buf] + ldst);
            GLDS(kl + gk, kls[buf] + ldst);
            GLDS(vt + gv, vs[buf]  + ldst);
        }
    };

    stage(0, 0);
    for (int kt = 0; kt < 16; ++kt) {
        const int cur = kt & 1;
        __syncthreads();   // drains stage(kt) (in flight since last iteration)
        if (kt + 1 < 16) stage(kt + 1, cur ^ 1);

        // S^T with permuted key tiles; exp; pack P into registers (PV B-frags)
        bf16x8 bp[2][2];
        #pragma unroll
        for (int tt = 0; tt < 4; ++tt) {
            const int rho = ((l15 >> 2) << 3) + ((tt & 1) << 2) + (l15 & 3) + ((tt >> 1) << 5);
            const int a0 = rho*64 + ((quad       ^ xs) * 8);
            const int a1 = rho*64 + (((quad | 4) ^ xs) * 8);
            const bf16x8 bh0 = *(const bf16x8*)(khs[cur] + a0);
            const bf16x8 bh1 = *(const bf16x8*)(khs[cur] + a1);
            const bf16x8 bl0 = *(const bf16x8*)(kls[cur] + a0);
            const bf16x8 bl1 = *(const bf16x8*)(kls[cur] + a1);
            #pragma unroll
            for (int rt = 0; rt < 2; ++rt) {
                floatx4 a = floatx4{0.f, 0.f, 0.f, 0.f};
                a = __builtin_amdgcn_mfma_f32_16x16x32_bf16(bh0, qfh[rt][0], a, 0, 0, 0);
                a = __builtin_amdgcn_mfma_f32_16x16x32_bf16(bh1, qfh[rt][1], a, 0, 0, 0);
                a = __builtin_amdgcn_mfma_f32_16x16x32_bf16(bl0, qfh[rt][0], a, 0, 0, 0);
                a = __builtin_amdgcn_mfma_f32_16x16x32_bf16(bl1, qfh[rt][1], a, 0, 0, 0);
                a = __builtin_amdgcn_mfma_f32_16x16x32_bf16(bh0, qfl[rt][0], a, 0, 0, 0);
                a = __builtin_amdgcn_mfma_f32_16x16x32_bf16(bh1, qfl[rt][1], a, 0, 0, 0);
                const float e0 = __expf(a[0] - EOFF);
                const float e1 = __expf(a[1] - EOFF);
                const float e2 = __expf(a[2] - EOFF);
                const float e3 = __expf(a[3] - EOFF);
                lsum[rt] += (e0 + e1) + (e2 + e3);
                bf16x8& dst = bp[rt][tt >> 1];
                const int off = (tt & 1) * 4;
                dst[off + 0] = (short)f2bf(e0);
                dst[off + 1] = (short)f2bf(e1);
                dst[off + 2] = (short)f2bf(e2);
                dst[off + 3] = (short)f2bf(e3);
            }
        }

        // O^T += V^T P^T ; V frags hoisted (read once, used by both rt)
        #pragma unroll
        for (int tc = 0; tc < 4; ++tc) {
            const int crow = (tc*16 + l15) * 64;
            const bf16x8 va0 = *(const bf16x8*)(vs[cur] + crow + ((quad       ^ xs) * 8));
            const bf16x8 va1 = *(const bf16x8*)(vs[cur] + crow + (((quad | 4) ^ xs) * 8));
            #pragma unroll
            for (int rt = 0; rt < 2; ++rt) {
                o[rt][tc] = __builtin_amdgcn_mfma_f32_16x16x32_bf16(va0, bp[rt][0], o[rt][tc], 0, 0, 0);
                o[rt][tc] = __builtin_amdgcn_mfma_f32_16x16x32_bf16(va1, bp[rt][1], o[rt][tc], 0, 0, 0);
            }
        }
    }

    // epilogue: reduce l across quads (lanes sharing l15), ctx = O/l + mask@V
    float inv[2];
    #pragma unroll
    for (int rt = 0; rt < 2; ++rt) {
        float l = lsum[rt];
        l += __shfl_xor(l, 16);
        l += __shfl_xor(l, 32);
        inv[rt] = 1.0f / l;
    }
    const float* mvp = mv + ((size_t)p * NH + h) * HSZ;
    #pragma unroll
    for (int rt = 0; rt < 2; ++rt) {
        const int row = qt*128 + w*32 + rt*16 + l15;
        const size_t base = ((size_t)p * NS + row) * DM + h * 64;
        #pragma unroll
        for (int tc = 0; tc < 4; ++tc) {
            const int c0 = tc*16 + quad*4;
            ushort4 pk;
            pk.x = f2bf(o[rt][tc][0] * inv[rt] + mvp[c0 + 0]);
            pk.y = f2bf(o[rt][tc][1] * inv[rt] + mvp[c0 + 1]);
            pk.z = f2bf(o[rt][tc][2] * inv[rt] + mvp[c0 + 2]);
            pk.w = f2bf(o[rt][tc][3] * inv[rt] + mvp[c0 + 3]);
            *(ushort4*)(ctx + base + c0) = pk;
        }
    }
}

extern "C" void kernel_launch(void* const* d_in, const int* in_sizes, int n_in,
                              void* d_out, int out_size, void* d_ws, size_t ws_size,
                              hipStream_t stream)
{
    const float* x      = (const float*)d_in[0];
    const float* mask   = (const float*)d_in[1];
    const float* qkv_w  = (const float*)d_in[2];
    const float* qkv_b  = (const float*)d_in[3];
    const float* proj_w = (const float*)d_in[4];
    const float* proj_b = (const float*)d_in[5];
    float* out = (float*)d_out;

    // workspace (~97.5 MB): x hi/lo dead after qkv GEMMs -> ctx (bf16) aliases xh.
    const size_t HE = (size_t)PB * NH * NS * HSZ;   // 6291456
    const size_t QW = (size_t)DM * 3 * DM;          // 1769472
    const size_t PW = (size_t)DM * DM;              // 589824
    ushort* xh  = (ushort*)d_ws;
    ushort* xl  = xh + HE;
    ushort* qwh = xl + HE;
    ushort* qwl = qwh + QW;
    ushort* pwh = qwl + QW;
    ushort* pwl = pwh + PW;
    ushort* qhv = pwl + PW;
    ushort* qlv = qhv + HE;
    ushort* khv = qlv + HE;
    ushort* klv = khv + HE;
    ushort* vtv = klv + HE;
    float*  mvb = (float*)(vtv + HE);
    ushort* cth = xh;   // alias: ctx bf16 over dead x_hi

    split_kernel<<<2048, 256, 0, stream>>>(x, xh, xl, (int)(HE / 4));
    splitT_kernel<<<dim3(3*DM/32, DM/32), dim3(32, 8), 0, stream>>>(qkv_w, qwh, qwl, DM, 3*DM);
    splitT_kernel<<<dim3(DM/32,   DM/32), dim3(32, 8), 0, stream>>>(proj_w, pwh, pwl, DM, DM);

    // q/k columns: 3-pass split GEMM (cols 0..1535); grid x=m for XCD locality
    gemm_qk<<<dim3(PB*NS/128, 12), 256, 0, stream>>>(
        xh, xl, qwh, qwl, qkv_b, qhv, qlv, khv, klv, DM);
    // v columns: single-pass BK=64 GEMM (cols 1536..2303 -> rows 1536.. of qwh)
    gemm_1p<2><<<dim3(PB*NS/128, DM/128), 256, 0, stream>>>(
        xh, qwh + (size_t)2*DM*DM, qkv_b + 2*DM, nullptr, vtv, DM);

    mv_kernel<<<dim3(PB*NH), 256, 0, stream>>>(mask, vtv, mvb);

    attn_mfma_kernel<<<dim3(PB*NH, NS/128), 256, 0, stream>>>(
        qhv, qlv, khv, klv, vtv, mvb, cth);

    gemm_1p<0><<<dim3(PB*NS/128, DM/128), 256, 0, stream>>>(
        cth, pwh, proj_b, out, nullptr, DM);
}

// Round 11
// 197.148 us; speedup vs baseline: 1.4091x; 1.4091x over previous
//
#include <hip/hip_runtime.h>
#include <hip/hip_bf16.h>
#include <cstdint>
#include <math.h>

constexpr int PB = 8;
constexpr int NS = 1024;
constexpr int DM = 768;
constexpr int NH = 12;
constexpr int HSZ = 64;
// reference MULTIPLIES scores by sqrt(head_size)=8; folded into q at qkv epilogue.
constexpr float EOFF = 88.0f;   // fixed softmax offset: p = exp(s-EOFF)/sum

typedef short bf16x8 __attribute__((ext_vector_type(8)));
typedef _Float16 half8 __attribute__((ext_vector_type(8)));
typedef float floatx4 __attribute__((ext_vector_type(4)));

__device__ __forceinline__ ushort f2bf(float x) {
    __hip_bfloat16 b = __float2bfloat16(x);
    return *reinterpret_cast<ushort*>(&b);
}
__device__ __forceinline__ float bf2f(ushort u) {
    __hip_bfloat16 b = *reinterpret_cast<__hip_bfloat16*>(&u);
    return __bfloat162float(b);
}
__device__ __forceinline__ ushort f2h(float x) {
    _Float16 h = (_Float16)x;
    return *reinterpret_cast<ushort*>(&h);
}

#define GLDS(g, l)                                                             \
    __builtin_amdgcn_global_load_lds(                                          \
        (const __attribute__((address_space(1))) void*)(g),                    \
        (__attribute__((address_space(3))) void*)(l), 16, 0, 0)

// ---------- split fp32 -> bf16 + f16, elementwise (x) ----------
__global__ void split_kernel(const float* __restrict__ x, ushort* __restrict__ bh,
                             ushort* __restrict__ hf, int n4)
{
    int i = blockIdx.x * blockDim.x + threadIdx.x;
    const int stride = gridDim.x * blockDim.x;
    for (; i < n4; i += stride) {
        const float4 v = ((const float4*)x)[i];
        ((ushort4*)bh)[i] = ushort4{f2bf(v.x), f2bf(v.y), f2bf(v.z), f2bf(v.w)};
        ((ushort4*)hf)[i] = ushort4{f2h(v.x),  f2h(v.y),  f2h(v.z),  f2h(v.w)};
    }
}

// ---------- transpose: w (K x N) -> wT bf16 (N x K) + optional f16 ----------
__global__ void splitT_kernel(const float* __restrict__ w, ushort* __restrict__ bT,
                              ushort* __restrict__ fT, int K, int N)
{
    __shared__ float tile[32][33];
    const int tx = threadIdx.x, ty = threadIdx.y;   // (32, 8)
    const int bx = blockIdx.x, by = blockIdx.y;     // N/32, K/32
    #pragma unroll
    for (int r = 0; r < 4; ++r)
        tile[ty + r*8][tx] = w[(size_t)(by*32 + ty + r*8) * N + bx*32 + tx];
    __syncthreads();
    #pragma unroll
    for (int r = 0; r < 4; ++r) {
        const int n = bx*32 + ty + r*8;
        const int k = by*32 + tx;
        const float v = tile[tx][ty + r*8];
        bT[(size_t)n * K + k] = f2bf(v);
        if (fT) fT[(size_t)n * K + k] = f2h(v);
    }
}

// ---------------- single-pass f16 MFMA GEMM for q/k columns ----------------
// C = A(MxK)@B(KxN) f16 inputs, fp32 acc. N = 1536 (q then k). 128x128 tile,
// BK=64 (32 MFMA/barrier). GRID: x=m(64), y=n(12) -> same-A blocks co-XCD.
// Epilogue: scatter q (x8) / k as f16 (P,H,N,64).
__global__ __launch_bounds__(256, 3)
void gemm_qkf(const ushort* __restrict__ Af, const ushort* __restrict__ Bf,
              const float* __restrict__ bias,
              ushort* __restrict__ qf, ushort* __restrict__ kf, int K)
{
    __shared__ __align__(16) ushort As[128*64];
    __shared__ __align__(16) ushort Bs[128*64];

    const int t    = threadIdx.x;
    const int w    = t >> 6;
    const int lane = t & 63;
    const int l15  = lane & 15;
    const int quad = lane >> 4;
    const int wm = w >> 1, wn = w & 1;
    const int m0 = blockIdx.x * 128, n0 = blockIdx.y * 128;

    floatx4 acc[4][4];
    #pragma unroll
    for (int i = 0; i < 4; ++i)
        #pragma unroll
        for (int j = 0; j < 4; ++j) acc[i][j] = floatx4{0.f, 0.f, 0.f, 0.f};

    const int srow8 = lane >> 3;
    const int sslot = lane & 7;

    for (int k0 = 0; k0 < K; k0 += 64) {
        #pragma unroll
        for (int j = 0; j < 4; ++j) {
            const int row = w*32 + j*8 + srow8;
            const int seg = sslot ^ (row & 7);
            const int ldst = (w*32 + j*8) * 64;
            GLDS(Af + (size_t)(m0 + row) * K + k0 + seg*8, As + ldst);
            GLDS(Bf + (size_t)(n0 + row) * K + k0 + seg*8, Bs + ldst);
        }
        __syncthreads();

        #pragma unroll
        for (int h2 = 0; h2 < 2; ++h2) {
            half8 fa[4], fb[4];
            #pragma unroll
            for (int i = 0; i < 4; ++i) {
                const int sl = ((h2*4 + quad) ^ (l15 & 7)) * 8;
                fa[i] = *(const half8*)(As + (wm*64 + i*16 + l15) * 64 + sl);
                fb[i] = *(const half8*)(Bs + (wn*64 + i*16 + l15) * 64 + sl);
            }
            #pragma unroll
            for (int mt = 0; mt < 4; ++mt)
                #pragma unroll
                for (int nt = 0; nt < 4; ++nt)
                    acc[mt][nt] = __builtin_amdgcn_mfma_f32_16x16x32_f16(fa[mt], fb[nt], acc[mt][nt], 0, 0, 0);
        }
        __syncthreads();
    }

    // scatter: cols j = c*768 + h*64 + s, c in {0,1}
    const int jbase = n0 + wn*64;
    const int c  = jbase / DM;
    const int hh = (jbase % DM) >> 6;
    const int pp = (m0 + wm*64) >> 10;
    const size_t head = (size_t)pp * NH + hh;
    ushort* dst = (c == 0 ? qf : kf);
    const float qscale = (c == 0) ? 8.0f : 1.0f;   // fold score scale into q (exact)
    #pragma unroll
    for (int nt = 0; nt < 4; ++nt) {
        const int s = nt*16 + l15;
        const float bval = bias[jbase + s];
        #pragma unroll
        for (int mt = 0; mt < 4; ++mt) {
            const int tok0 = m0 + wm*64 + mt*16 + quad*4;
            const int nn0  = tok0 & 1023;
            #pragma unroll
            for (int r = 0; r < 4; ++r)
                dst[(head*NS + nn0 + r) * HSZ + s] = f2h((acc[mt][nt][r] + bval) * qscale);
        }
    }
}

// ---------------- single-pass bf16 MFMA GEMM, BK=64 (V + proj) ----------------
// GRID: x = m-block (64), y = n-block -> same-A blocks share an XCD.
template <int MODE>
__global__ __launch_bounds__(256, 3)
void gemm_1p(const ushort* __restrict__ Ah, const ushort* __restrict__ Bh,
             const float* __restrict__ bias, float* __restrict__ outf,
             ushort* __restrict__ vt, int K)
{
    __shared__ __align__(16) ushort As[128*64];
    __shared__ __align__(16) ushort Bs[128*64];

    const int t    = threadIdx.x;
    const int w    = t >> 6;
    const int lane = t & 63;
    const int l15  = lane & 15;
    const int quad = lane >> 4;
    const int wm = w >> 1, wn = w & 1;
    const int m0 = blockIdx.x * 128, n0 = blockIdx.y * 128;

    floatx4 acc[4][4];
    #pragma unroll
    for (int i = 0; i < 4; ++i)
        #pragma unroll
        for (int j = 0; j < 4; ++j) acc[i][j] = floatx4{0.f, 0.f, 0.f, 0.f};

    const int srow8 = lane >> 3;
    const int sslot = lane & 7;

    for (int k0 = 0; k0 < K; k0 += 64) {
        #pragma unroll
        for (int j = 0; j < 4; ++j) {
            const int row = w*32 + j*8 + srow8;
            const int seg = sslot ^ (row & 7);
            const int ldst = (w*32 + j*8) * 64;
            GLDS(Ah + (size_t)(m0 + row) * K + k0 + seg*8, As + ldst);
            GLDS(Bh + (size_t)(n0 + row) * K + k0 + seg*8, Bs + ldst);
        }
        __syncthreads();

        #pragma unroll
        for (int h2 = 0; h2 < 2; ++h2) {
            bf16x8 fa[4], fb[4];
            #pragma unroll
            for (int i = 0; i < 4; ++i) {
                const int sl = ((h2*4 + quad) ^ (l15 & 7)) * 8;
                fa[i] = *(const bf16x8*)(As + (wm*64 + i*16 + l15) * 64 + sl);
                fb[i] = *(const bf16x8*)(Bs + (wn*64 + i*16 + l15) * 64 + sl);
            }
            #pragma unroll
            for (int mt = 0; mt < 4; ++mt)
                #pragma unroll
                for (int nt = 0; nt < 4; ++nt)
                    acc[mt][nt] = __builtin_amdgcn_mfma_f32_16x16x32_bf16(fa[mt], fb[nt], acc[mt][nt], 0, 0, 0);
        }
        __syncthreads();
    }

    if (MODE == 0) {
        #pragma unroll
        for (int nt = 0; nt < 4; ++nt) {
            const int col = n0 + wn*64 + nt*16 + l15;
            const float bval = bias[col];
            #pragma unroll
            for (int mt = 0; mt < 4; ++mt) {
                const int row0 = m0 + wm*64 + mt*16 + quad*4;
                #pragma unroll
                for (int r = 0; r < 4; ++r)
                    outf[(size_t)(row0 + r) * DM + col] = acc[mt][nt][r] + bval;
            }
        }
    } else {
        const int jbase = n0 + wn*64;
        const int hh = jbase >> 6;
        const int pp = (m0 + wm*64) >> 10;
        const size_t head = (size_t)pp * NH + hh;
        #pragma unroll
        for (int nt = 0; nt < 4; ++nt) {
            const int s = nt*16 + l15;
            const float bval = bias[jbase + s];
            #pragma unroll
            for (int mt = 0; mt < 4; ++mt) {
                const int tok0 = m0 + wm*64 + mt*16 + quad*4;
                const int nn0  = tok0 & 1023;
                ushort4 pk;
                pk.x = f2bf(acc[mt][nt][0] + bval);
                pk.y = f2bf(acc[mt][nt][1] + bval);
                pk.z = f2bf(acc[mt][nt][2] + bval);
                pk.w = f2bf(acc[mt][nt][3] + bval);
                *(ushort4*)(vt + (head*HSZ + s) * NS + nn0) = pk;
            }
        }
    }
}

// ---------------- mask @ V per (p,h): mv[p][h][c] ----------------
__global__ void mv_kernel(const float* __restrict__ mask, const ushort* __restrict__ vt,
                          float* __restrict__ mv)
{
    __shared__ float red[4][64];
    const int ph = blockIdx.x;
    const int t  = threadIdx.x;
    const int c  = t & 63, part = t >> 6;
    const ushort* vrow = vt + ((size_t)ph * HSZ + c) * NS + part * 256;
    const float*  mrow = mask + (size_t)(ph / NH) * NS + part * 256;
    float acc = 0.f;
    for (int k = 0; k < 256; k += 4) {
        const ushort4 v4 = *(const ushort4*)(vrow + k);
        const float4  m4 = *(const float4*)(mrow + k);
        acc += m4.x * bf2f(v4.x) + m4.y * bf2f(v4.y)
             + m4.z * bf2f(v4.z) + m4.w * bf2f(v4.w);
    }
    red[part][c] = acc;
    __syncthreads();
    if (t < 64)
        mv[(size_t)ph * HSZ + t] = red[0][t] + red[1][t] + red[2][t] + red[3][t];
}

// ---------------- MFMA flash attention, f16 QK + q-tile 64 ----------------
// GRID: x = ph (96), y = qt (16); id%8 = ph%8 pins all q-tiles of one (p,h)
// to one XCD (r9: FETCH 197->46 MB). r9/r10 were phase-serialization-bound at
// 3 grid-limited blocks/CU (MFMA 26 / VALU 36 / HBM 10). Fix: q-tile 64 ->
// 1536 blocks (6/CU potential), f16 single-pass S (2 MFMA per 16x16 S-tile,
// was 6), 16 KB single LDS buffer. min-waves 5 -> VGPR cap 102 (state ~70;
// r8 showed forcing past the state floor spills catastrophically).
// S^T = K.Q^T permuted-key kappa(t,quad,r)=quad*8+(t&1)*4+r+(t>>1)*32: post-exp
// values land in the PV B-frag layout (register P). Fixed-offset softmax
// exp(s-88); l reduced once in epilogue. ctx = O/l + mv (exact post-softmax
// mask-add), bf16. PV stays bf16 (V is bf16).
__global__ __launch_bounds__(256, 5)
void attn_mfma_kernel(const ushort* __restrict__ qf, const ushort* __restrict__ kf,
                      const ushort* __restrict__ vt, const float* __restrict__ mv,
                      ushort* __restrict__ ctx)
{
    __shared__ __align__(16) ushort khs[64*64];   // f16 bits
    __shared__ __align__(16) ushort vs [64*64];   // bf16 bits

    const int t    = threadIdx.x;
    const int w    = t >> 6;
    const int lane = t & 63;
    const int l15  = lane & 15;
    const int quad = lane >> 4;
    const int ph = blockIdx.x, qt = blockIdx.y;    // XCD swizzle
    const int h  = ph % NH,    p  = ph / NH;
    const size_t headoff = ((size_t)p * NH + h) * (size_t)(NS * HSZ);

    // persistent Q frags (B-operand, f16): row = qt*64 + w*16 + l15
    const ushort* qb = qf + headoff + (size_t)(qt*64 + w*16 + l15) * HSZ + quad*8;
    const half8 qfr0 = *(const half8*)(qb);
    const half8 qfr1 = *(const half8*)(qb + 32);

    floatx4 o[4];
    float lsum = 0.f;
    #pragma unroll
    for (int tc = 0; tc < 4; ++tc) o[tc] = floatx4{0.f, 0.f, 0.f, 0.f};

    const int srow8 = lane >> 3;
    const int sslot = lane & 7;
    const int xs = l15 & 7;         // read-side unswizzle key

    for (int kt = 0; kt < 16; ++kt) {
        __syncthreads();   // previous tile's LDS reads complete
        #pragma unroll
        for (int j = 0; j < 2; ++j) {
            const int row  = w*16 + j*8 + srow8;                       // 0..63
            const int segK = sslot ^ ((row & 3) | (((row >> 3) & 1) << 2));
            const int segV = sslot ^ (row & 7);
            const size_t gk = headoff + (size_t)(kt*64 + row) * HSZ + segK*8;
            const size_t gv = headoff + (size_t)row * NS + kt*64 + segV*8;
            const int ldst = (w*16 + j*8) * 64;
            GLDS(kf + gk, khs + ldst);
            GLDS(vt + gv, vs  + ldst);
        }
        __syncthreads();   // staged data visible

        // S^T with permuted key tiles; exp; pack P into registers (PV B-frags)
        bf16x8 bp[2];
        #pragma unroll
        for (int tt = 0; tt < 4; ++tt) {
            const int rho = ((l15 >> 2) << 3) + ((tt & 1) << 2) + (l15 & 3) + ((tt >> 1) << 5);
            const int a0 = rho*64 + ((quad       ^ xs) * 8);
            const int a1 = rho*64 + (((quad | 4) ^ xs) * 8);
            const half8 bh0 = *(const half8*)(khs + a0);
            const half8 bh1 = *(const half8*)(khs + a1);
            floatx4 a = floatx4{0.f, 0.f, 0.f, 0.f};
            a = __builtin_amdgcn_mfma_f32_16x16x32_f16(bh0, qfr0, a, 0, 0, 0);
            a = __builtin_amdgcn_mfma_f32_16x16x32_f16(bh1, qfr1, a, 0, 0, 0);
            const float e0 = __expf(a[0] - EOFF);
            const float e1 = __expf(a[1] - EOFF);
            const float e2 = __expf(a[2] - EOFF);
            const float e3 = __expf(a[3] - EOFF);
            lsum += (e0 + e1) + (e2 + e3);
            bf16x8& dst = bp[tt >> 1];
            const int off = (tt & 1) * 4;
            dst[off + 0] = (short)f2bf(e0);
            dst[off + 1] = (short)f2bf(e1);
            dst[off + 2] = (short)f2bf(e2);
            dst[off + 3] = (short)f2bf(e3);
        }

        // O^T += V^T P^T
        #pragma unroll
        for (int tc = 0; tc < 4; ++tc) {
            const int crow = (tc*16 + l15) * 64;
            const bf16x8 va0 = *(const bf16x8*)(vs + crow + ((quad       ^ xs) * 8));
            const bf16x8 va1 = *(const bf16x8*)(vs + crow + (((quad | 4) ^ xs) * 8));
            o[tc] = __builtin_amdgcn_mfma_f32_16x16x32_bf16(va0, bp[0], o[tc], 0, 0, 0);
            o[tc] = __builtin_amdgcn_mfma_f32_16x16x32_bf16(va1, bp[1], o[tc], 0, 0, 0);
        }
    }

    // epilogue: reduce l across quads (lanes sharing l15), ctx = O/l + mask@V
    float l = lsum;
    l += __shfl_xor(l, 16);
    l += __shfl_xor(l, 32);
    const float inv = 1.0f / l;

    const float* mvp = mv + ((size_t)p * NH + h) * HSZ;
    const int row = qt*64 + w*16 + l15;
    const size_t base = ((size_t)p * NS + row) * DM + h * 64;
    #pragma unroll
    for (int tc = 0; tc < 4; ++tc) {
        const int c0 = tc*16 + quad*4;
        ushort4 pk;
        pk.x = f2bf(o[tc][0] * inv + mvp[c0 + 0]);
        pk.y = f2bf(o[tc][1] * inv + mvp[c0 + 1]);
        pk.z = f2bf(o[tc][2] * inv + mvp[c0 + 2]);
        pk.w = f2bf(o[tc][3] * inv + mvp[c0 + 3]);
        *(ushort4*)(ctx + base + c0) = pk;
    }
}

extern "C" void kernel_launch(void* const* d_in, const int* in_sizes, int n_in,
                              void* d_out, int out_size, void* d_ws, size_t ws_size,
                              hipStream_t stream)
{
    const float* x      = (const float*)d_in[0];
    const float* mask   = (const float*)d_in[1];
    const float* qkv_w  = (const float*)d_in[2];
    const float* qkv_b  = (const float*)d_in[3];
    const float* proj_w = (const float*)d_in[4];
    const float* proj_b = (const float*)d_in[5];
    float* out = (float*)d_out;

    // workspace (~71 MB): xh/xf dead after GEMMs -> ctx (bf16) aliases xh.
    const size_t HE = (size_t)PB * NH * NS * HSZ;   // 6291456
    const size_t QW = (size_t)DM * 3 * DM;          // 1769472
    const size_t PW = (size_t)DM * DM;              // 589824
    ushort* xh  = (ushort*)d_ws;        // x bf16 (V GEMM A)
    ushort* xf  = xh + HE;              // x f16 (qk GEMM A)
    ushort* qwh = xf + HE;              // qkv_w^T bf16 (V GEMM B)
    ushort* qwf = qwh + QW;             // qkv_w^T f16 (qk GEMM B)
    ushort* pwh = qwf + QW;             // proj_w^T bf16
    ushort* qfv = pwh + PW;             // q f16 (P,H,N,64), pre-scaled x8
    ushort* kfv = qfv + HE;             // k f16
    ushort* vtv = kfv + HE;             // v^T bf16 (P,H,64,N)
    float*  mvb = (float*)(vtv + HE);
    ushort* cth = xh;   // alias: ctx bf16 over dead x_bf16

    split_kernel<<<2048, 256, 0, stream>>>(x, xh, xf, (int)(HE / 4));
    splitT_kernel<<<dim3(3*DM/32, DM/32), dim3(32, 8), 0, stream>>>(qkv_w, qwh, qwf, DM, 3*DM);
    splitT_kernel<<<dim3(DM/32,   DM/32), dim3(32, 8), 0, stream>>>(proj_w, pwh, nullptr, DM, DM);

    // q/k columns: single-pass f16 GEMM (cols 0..1535)
    gemm_qkf<<<dim3(PB*NS/128, 12), 256, 0, stream>>>(
        xf, qwf, qkv_b, qfv, kfv, DM);
    // v columns: single-pass bf16 GEMM (cols 1536..2303 -> rows 1536.. of qwh)
    gemm_1p<2><<<dim3(PB*NS/128, DM/128), 256, 0, stream>>>(
        xh, qwh + (size_t)2*DM*DM, qkv_b + 2*DM, nullptr, vtv, DM);

    mv_kernel<<<dim3(PB*NH), 256, 0, stream>>>(mask, vtv, mvb);

    attn_mfma_kernel<<<dim3(PB*NH, NS/64), 256, 0, stream>>>(
        qfv, kfv, vtv, mvb, cth);

    gemm_1p<0><<<dim3(PB*NS/128, DM/128), 256, 0, stream>>>(
        cth, pwh, proj_b, out, nullptr, DM);
}